// Round 4
// baseline (232.649 us; speedup 1.0000x reference)
//
#include <hip/hip_runtime.h>
#include <math.h>

#define S 128
#define KA 25
#define KL 25
#define PATCH 625
#define FEAT 1250
#define PI_F 3.14159265358979323846f

// d_ws layout (floats):
//   [0, 625)            normalized LRI_ENV
//   [640, 640+16384)    lat0 = relu(raw_aff - ada)
//   [17024, 17024+1024) per-block corr partials
#define WS_ENV 0
#define WS_LAT0 640
#define WS_PART 17024

// ---------------------------------------------------------------------------
// Kernel 1: tiles + raw_aff for an l-PAIR per block (p -> l=2p, 2p+1).
// rfs float4 loads at element 2500p (16B-aligned).  tiles stores as float4 at
// out-element 32768 + 2500p + 4k (16B-aligned): windows cover pair-local
// f' in [-1, 2498]; the f'=-1 element belongs to the previous pair and is
// computed here (decode handles it); global element -1 is the corr slot
// (garbage, overwritten by k_reduce).  Last block scalar-stores the final
// element.  t computed for 5 elements/window: t[0..3] -> store, t[1..4] -> dot.
// ---------------------------------------------------------------------------
__global__ __launch_bounds__(256) void k_tiles_aff(const float* __restrict__ x,
                                                   const float* __restrict__ rfs,
                                                   const float* __restrict__ ada,
                                                   float* __restrict__ raw_aff,
                                                   float* __restrict__ tiles, // out+32769
                                                   float* __restrict__ ws) {
    __shared__ float s_ae[PATCH];
    __shared__ float s_part[8];
    const int tid = threadIdx.x;
    const int lane = tid & 63;
    const int wv = tid >> 6;

    for (int i = tid; i < PATCH; i += 256) {
        float di = (float)(i / KA) - 12.0f;
        float dj = (float)(i % KA) - 12.0f;
        float d = sqrtf(di * di + dj * dj);
        float v = 0.0f;
        if (d < 12.5f) { float c = cosf(d * (PI_F / 25.0f)); v = c * c; }
        s_ae[i] = v;   // AFF env, max exactly 1 at center
    }
    __syncthreads();

    const int p = blockIdx.x;               // pair id, 0..8191
    const long pbase = (long)p * 2500;
    const float4* __restrict__ rfs4 = (const float4*)(rfs + pbase);
    float4* __restrict__ st4 = (float4*)(tiles + pbase - 1);   // 16B-aligned

    float acc0 = 0.0f, acc1 = 0.0f;
    for (int k = tid; k < 625; k += 256) {
        float t[5];
#pragma unroll
        for (int e = 0; e < 5; ++e) {
            int fp = 4 * k - 1 + e;          // pair-local f' in [-1, 2499]
            int u = fp + 1250;
            int li_ = u / 1250;              // 0,1,2
            int f = u - 1250 * li_;          // [0, 1250)
            int l = 2 * p + li_ - 1;
            if (l < 0) l = 0;                // p==0, f'=-1: garbage slot, stay in-bounds
            int c = f >= 625;
            int r = f - 625 * c;
            int ki = r / 25;
            int kj = r - 25 * ki;
            int li = l >> 7, lj = l & 127;
            t[e] = x[c * (152 * 152) + (li + ki) * 152 + (lj + kj)] * s_ae[r];
        }
        st4[k] = make_float4(t[0], t[1], t[2], t[3]);
        float4 rv = rfs4[k];
        // dot elements f' = 4k+e use t[e+1]
        if (4 * k + 3 < 1250) {              // window fully in l=2p
            acc0 += t[1] * fmaxf(rv.x, 0.f) + t[2] * fmaxf(rv.y, 0.f)
                  + t[3] * fmaxf(rv.z, 0.f) + t[4] * fmaxf(rv.w, 0.f);
        } else if (4 * k >= 1250) {          // fully in l=2p+1
            acc1 += t[1] * fmaxf(rv.x, 0.f) + t[2] * fmaxf(rv.y, 0.f)
                  + t[3] * fmaxf(rv.z, 0.f) + t[4] * fmaxf(rv.w, 0.f);
        } else {                             // k==312: 1248,1249 | 1250,1251
            acc0 += t[1] * fmaxf(rv.x, 0.f) + t[2] * fmaxf(rv.y, 0.f);
            acc1 += t[3] * fmaxf(rv.z, 0.f) + t[4] * fmaxf(rv.w, 0.f);
        }
    }

    // last global tiles element (l=16383, f=1249) not covered by any window
    if (p == 8191 && tid == 0) {
        tiles[pbase + 2499] = x[152 * 152 + 151 * 152 + 151] * s_ae[624];
    }

    for (int off = 32; off > 0; off >>= 1) {
        acc0 += __shfl_down(acc0, off);
        acc1 += __shfl_down(acc1, off);
    }
    if (lane == 0) { s_part[wv] = acc0; s_part[4 + wv] = acc1; }
    __syncthreads();
    if (tid == 0) {
        float ra0 = s_part[0] + s_part[1] + s_part[2] + s_part[3];
        float ra1 = s_part[4] + s_part[5] + s_part[6] + s_part[7];
        int l0 = 2 * p;
        raw_aff[l0] = ra0;
        raw_aff[l0 + 1] = ra1;
        ws[WS_LAT0 + l0] = fmaxf(ra0 - ada[l0], 0.0f);
        ws[WS_LAT0 + l0 + 1] = fmaxf(ra1 - ada[l0 + 1], 0.0f);
    }

    // Block 0 builds the normalized LRI envelope into ws.
    if (blockIdx.x == 0) {
        __syncthreads();   // s_ae / s_part reuse
        float m = 0.0f;
        for (int i = tid; i < PATCH; i += 256) {
            float di = (float)(i / KL) - 12.0f;
            float dj = (float)(i % KL) - 12.0f;
            float d = sqrtf(di * di + dj * dj);
            float v = 0.0f;
            if (d < 12.5f) {
                float c1 = cosf(d * (PI_F / 25.0f));
                float inh = 0.0f;
                if (d < 4.5f) { float c2 = cosf(d * (PI_F / 9.0f)); inh = c2 * c2; }
                v = c1 * c1 * (1.0f - inh);
            }
            s_ae[i] = v;
            m = fmaxf(m, v);
        }
        for (int off = 32; off > 0; off >>= 1) m = fmaxf(m, __shfl_down(m, off));
        if (lane == 0) s_part[wv] = m;
        __syncthreads();
        float inv = 1.0f / fmaxf(fmaxf(s_part[0], s_part[1]),
                                 fmaxf(s_part[2], s_part[3]));
        for (int i = tid; i < PATCH; i += 256) ws[WS_ENV + i] = s_ae[i] * inv;
    }
}

// ---------------------------------------------------------------------------
// Kernel 2: final lat.  One WAVE per l-quad (q -> l=4q..4q+3): lw float4
// loads at element 2500q (16B-aligned).  Per-element select into 4 accs.
// lat_neg[l] = sum_f pad0(lat0)[nbr(l,f)] * le[f] * relu(lw[l,f])
// latf[l] = tanh(relu(lat0[l] - lat_neg + aff[l]))
// ---------------------------------------------------------------------------
__global__ __launch_bounds__(256) void k_lat(const float* __restrict__ raw_aff,
                                             const float* __restrict__ ada,
                                             const float* __restrict__ lw,
                                             float* __restrict__ latf,
                                             const float* __restrict__ ws) {
    __shared__ float s_le[PATCH];
    const int tid = threadIdx.x;
    for (int i = tid; i < PATCH; i += 256) s_le[i] = ws[WS_ENV + i];
    __syncthreads();

    const int lane = tid & 63;
    const int wv = tid >> 6;
    const int q = blockIdx.x * 4 + wv;       // quad id, 0..4095
    const int l0 = q * 4;
    const float4* __restrict__ lw4 = (const float4*)(lw + (long)q * 2500);
    const float* __restrict__ lat0 = ws + WS_LAT0;

    float a0 = 0.f, a1 = 0.f, a2 = 0.f, a3 = 0.f;
    for (int k = lane; k < 625; k += 64) {
        float4 w4 = lw4[k];
        float w[4] = { w4.x, w4.y, w4.z, w4.w };
#pragma unroll
        for (int e = 0; e < 4; ++e) {
            int fp = 4 * k + e;              // quad-local f' in [0, 2500)
            int li_ = fp / 625;              // which l of the quad
            int r = fp - 625 * li_;
            int ki = r / 25;
            int kj = r - 25 * ki;
            int l = l0 + li_;
            int ri = (l >> 7) + ki - 12;
            int rj = (l & 127) + kj - 12;
            float lv = 0.0f;
            if (ri >= 0 && ri < S && rj >= 0 && rj < S) lv = lat0[ri * S + rj];
            float contrib = lv * s_le[r] * fmaxf(w[e], 0.0f);
            a0 += (li_ == 0) ? contrib : 0.0f;
            a1 += (li_ == 1) ? contrib : 0.0f;
            a2 += (li_ == 2) ? contrib : 0.0f;
            a3 += (li_ == 3) ? contrib : 0.0f;
        }
    }
    for (int off = 32; off > 0; off >>= 1) {
        a0 += __shfl_down(a0, off); a1 += __shfl_down(a1, off);
        a2 += __shfl_down(a2, off); a3 += __shfl_down(a3, off);
    }
    if (lane == 0) {
        float acc[4] = { a0, a1, a2, a3 };
#pragma unroll
        for (int j = 0; j < 4; ++j) {
            int l = l0 + j;
            float aff_l = raw_aff[l] - ada[l];
            float v = fmaxf(aff_l, 0.0f) - acc[j] + aff_l;   // STRENGTH=1
            latf[l] = tanhf(fmaxf(v, 0.0f));
        }
    }
}

// ---------------------------------------------------------------------------
// Kernel 3: corr partials.  Same wave-per-quad structure, pad = 0.04,
// partial = sum_l latf[l] * (gather . relu(lw)); one ws write per block.
// ---------------------------------------------------------------------------
__global__ __launch_bounds__(256) void k_corr(const float* __restrict__ latf,
                                              const float* __restrict__ lw,
                                              float* __restrict__ ws) {
    __shared__ float s_le[PATCH];
    __shared__ float s_part[4];
    const int tid = threadIdx.x;
    for (int i = tid; i < PATCH; i += 256) s_le[i] = ws[WS_ENV + i];
    __syncthreads();

    const int lane = tid & 63;
    const int wv = tid >> 6;
    const int q = blockIdx.x * 4 + wv;
    const int l0 = q * 4;
    const float4* __restrict__ lw4 = (const float4*)(lw + (long)q * 2500);

    float a0 = 0.f, a1 = 0.f, a2 = 0.f, a3 = 0.f;
    for (int k = lane; k < 625; k += 64) {
        float4 w4 = lw4[k];
        float w[4] = { w4.x, w4.y, w4.z, w4.w };
#pragma unroll
        for (int e = 0; e < 4; ++e) {
            int fp = 4 * k + e;
            int li_ = fp / 625;
            int r = fp - 625 * li_;
            int ki = r / 25;
            int kj = r - 25 * ki;
            int l = l0 + li_;
            int ri = (l >> 7) + ki - 12;
            int rj = (l & 127) + kj - 12;
            float lv = 0.04f;                // HOMEO_TARGET padding
            if (ri >= 0 && ri < S && rj >= 0 && rj < S) lv = latf[ri * S + rj];
            float contrib = lv * s_le[r] * fmaxf(w[e], 0.0f);
            a0 += (li_ == 0) ? contrib : 0.0f;
            a1 += (li_ == 1) ? contrib : 0.0f;
            a2 += (li_ == 2) ? contrib : 0.0f;
            a3 += (li_ == 3) ? contrib : 0.0f;
        }
    }
    for (int off = 32; off > 0; off >>= 1) {
        a0 += __shfl_down(a0, off); a1 += __shfl_down(a1, off);
        a2 += __shfl_down(a2, off); a3 += __shfl_down(a3, off);
    }
    if (lane == 0) {
        s_part[wv] = a0 * latf[l0] + a1 * latf[l0 + 1]
                   + a2 * latf[l0 + 2] + a3 * latf[l0 + 3];
    }
    __syncthreads();
    if (tid == 0)
        ws[WS_PART + blockIdx.x] = s_part[0] + s_part[1] + s_part[2] + s_part[3];
}

// ---------------------------------------------------------------------------
// Kernel 4: deterministic sum of 1024 partials -> corr scalar.
// ---------------------------------------------------------------------------
__global__ __launch_bounds__(256) void k_reduce(const float* __restrict__ ws,
                                                float* __restrict__ corr) {
    __shared__ float s_part[4];
    const int tid = threadIdx.x;
    const int lane = tid & 63;
    const int wv = tid >> 6;
    float acc = 0.0f;
    for (int i = tid; i < 1024; i += 256) acc += ws[WS_PART + i];
    for (int off = 32; off > 0; off >>= 1) acc += __shfl_down(acc, off);
    if (lane == 0) s_part[wv] = acc;
    __syncthreads();
    if (tid == 0) corr[0] = s_part[0] + s_part[1] + s_part[2] + s_part[3];
}

// ---------------------------------------------------------------------------
// d_out layout (flat, return order):
//   [0, 16384)              raw_aff   [1,1,128,128]
//   [16384, 32768)          lat       [1,1,128,128]
//   [32768]                 lat_correlations (scalar)
//   [32769, 32769+20480000) tiles     [16384, 1, 1250]
// ---------------------------------------------------------------------------
extern "C" void kernel_launch(void* const* d_in, const int* in_sizes, int n_in,
                              void* d_out, int out_size, void* d_ws, size_t ws_size,
                              hipStream_t stream) {
    const float* x   = (const float*)d_in[0];   // [1,2,152,152]
    const float* rfs = (const float*)d_in[1];   // [16384,1250,1]
    const float* lw  = (const float*)d_in[2];   // [16384,625,1]
    const float* ada = (const float*)d_in[3];   // [1,1,128,128]

    float* out      = (float*)d_out;
    float* raw_aff  = out;
    float* latf     = out + S * S;
    float* corr     = out + 2 * S * S;
    float* tiles    = out + 2 * S * S + 1;
    float* ws       = (float*)d_ws;

    k_tiles_aff<<<(S * S) / 2, 256, 0, stream>>>(x, rfs, ada, raw_aff, tiles, ws);
    k_lat<<<(S * S) / 16, 256, 0, stream>>>(raw_aff, ada, lw, latf, ws);
    k_corr<<<(S * S) / 16, 256, 0, stream>>>(latf, lw, ws);
    k_reduce<<<1, 256, 0, stream>>>(ws, corr);
}